// Round 11
// baseline (132.172 us; speedup 1.0000x reference)
//
#include <hip/hip_runtime.h>

#define N_TOTAL 16384
#define HALF    8192
#define FEAT    128
#define MARGIN  0.3f
#define NBINS   1024   // NUM_IDS=1000 <= 1024

typedef __attribute__((ext_vector_type(8))) short  short8v;   // 8 x bf16 (4 VGPRs)
typedef __attribute__((ext_vector_type(4))) float  float4v;   // 4 x f32 acc

__device__ __forceinline__ unsigned short f32_to_bf16_rne(float f) {
    unsigned u = __float_as_uint(f);
    u += 0x7FFFu + ((u >> 16) & 1u);
    return (unsigned short)(u >> 16);
}

// ---- DPP cross-lane min/max within 16-lane rows (VALU pipe, not DS) ------
template<int CTRL>
__device__ __forceinline__ float dpp_mov_f(float x) {
    return __int_as_float(__builtin_amdgcn_update_dpp(
        0, __float_as_int(x), CTRL, 0xF, 0xF, true));
}
__device__ __forceinline__ float rowmin16(float x) {
    x = fminf(x, dpp_mov_f<0xB1>(x));    // quad_perm xor1
    x = fminf(x, dpp_mov_f<0x4E>(x));    // quad_perm xor2
    x = fminf(x, dpp_mov_f<0x141>(x));   // ROW_HALF_MIRROR
    x = fminf(x, dpp_mov_f<0x140>(x));   // ROW_MIRROR
    return x;
}
__device__ __forceinline__ float rowmax16(float x) {
    x = fmaxf(x, dpp_mov_f<0xB1>(x));
    x = fmaxf(x, dpp_mov_f<0x4E>(x));
    x = fmaxf(x, dpp_mov_f<0x141>(x));
    x = fmaxf(x, dpp_mov_f<0x140>(x));
    return x;
}

// ---------------------------------------------------------------------------
// histscan: 2 blocks x 1024 (one per modality half). LDS histogram + scan ->
// cursor (bucket starts). Block 0 zeroes accF/accI/ticket.
// ---------------------------------------------------------------------------
__global__ __launch_bounds__(1024) void histscan_kernel(
        const int* __restrict__ targets, int* __restrict__ cursor,
        int* __restrict__ accs /* [accF, accI, ticket] */) {
    __shared__ int lhist[NBINS];
    const int h = blockIdx.x;
    const int t = threadIdx.x;
    lhist[t] = 0;
    __syncthreads();
    const int* tg = targets + (h << 13);
    #pragma unroll
    for (int k = 0; k < 8; ++k)
        atomicAdd(&lhist[tg[k * 1024 + t]], 1);
    __syncthreads();
    const int lane = t & 63, wave = t >> 6;
    int x = lhist[t];
    const int orig = x;
    #pragma unroll
    for (int m = 1; m < 64; m <<= 1) {
        int v = __shfl_up(x, m, 64);
        if (lane >= m) x += v;
    }
    __shared__ int wsum[16];
    if (lane == 63) wsum[wave] = x;
    __syncthreads();
    if (t == 0) {
        int s = 0;
        for (int w = 0; w < 16; ++w) { int v = wsum[w]; wsum[w] = s; s += v; }
        if (h == 0) { accs[0] = 0; accs[1] = 0; accs[2] = 0; }
    }
    __syncthreads();
    cursor[(h << 10) + t] = x - orig + wsum[wave];
}

// ---------------------------------------------------------------------------
// prep: one wave per ORIGINAL row. Claims sorted slot, converts fp32->bf16,
// writes Xb ROW-MAJOR (256 B/row), bf16 row norms, labels.
// ---------------------------------------------------------------------------
__global__ __launch_bounds__(256) void prep_kernel(
        const float* __restrict__ X, const int* __restrict__ targets,
        int* __restrict__ cursor,
        unsigned* __restrict__ Xb, float* __restrict__ sq, int* __restrict__ labs) {
    const int wave = threadIdx.x >> 6, lane = threadIdx.x & 63;
    const int src = blockIdx.x * 4 + wave;          // original row
    const int h   = src >> 13;
    const int lbl = targets[src];
    int dst;
    if (lane == 0)
        dst = (h << 13) + atomicAdd(&cursor[(h << 10) + lbl], 1);
    dst = __shfl(dst, 0, 64);
    const float2 xv = ((const float2*)(X + (size_t)src * FEAT))[lane];
    unsigned short h0 = f32_to_bf16_rne(xv.x);
    unsigned short h1 = f32_to_bf16_rne(xv.y);
    Xb[dst * 64 + lane] = (unsigned)h0 | ((unsigned)h1 << 16);
    float x0 = __uint_as_float((unsigned)h0 << 16);
    float x1 = __uint_as_float((unsigned)h1 << 16);
    float p = x0 * x0 + x1 * x1;
    #pragma unroll
    for (int m = 1; m < 64; m <<= 1) p += __shfl_xor(p, m, 64);
    if (lane == 0) {
        sq[dst]   = p;
        labs[dst] = lbl;
    }
}

// ---------------------------------------------------------------------------
// main: round-3 structure (128x128 LDS tile, 4096 blocks = 16-deep queue per
// CU, XOR-swizzled staging, 4 waves x 64x64 quadrant) with the atomic
// epilogue replaced by WRITE-ONCE partial stores (no contention, no RMW):
//   prow[bn*2 + (wave&1)][row]  and  pcol[bm*2 + (wave>>1)][col].
// ---------------------------------------------------------------------------
__global__ __launch_bounds__(256, 2) void cross_kernel(
        const unsigned short* __restrict__ Xb, const float* __restrict__ sq,
        const int* __restrict__ labs,
        float* __restrict__ prow_min, float* __restrict__ prow_max,   // [128][HALF]
        float* __restrict__ pcol_min, float* __restrict__ pcol_max) { // [128][HALF]
    __shared__ unsigned short As[128 * 128];
    __shared__ unsigned short Bs[128 * 128];
    const int bm = blockIdx.x, bn = blockIdx.y;
    const int t  = threadIdx.x;

    const unsigned short* Ag = Xb + (size_t)bm * 128 * FEAT;
    const unsigned short* Bg = Xb + (size_t)(HALF + bn * 128) * FEAT;
    #pragma unroll
    for (int p = 0; p < 8; ++p) {
        int idx = p * 256 + t;            // 16B chunk id, 0..2047
        int row = idx >> 4, ch = idx & 15;
        int sc  = ch ^ (row & 7);
        uint4 va = ((const uint4*)Ag)[idx];
        uint4 vb = ((const uint4*)Bg)[idx];
        *(uint4*)&As[row * 128 + sc * 8] = va;
        *(uint4*)&Bs[row * 128 + sc * 8] = vb;
    }
    __syncthreads();

    const int wave = t >> 6, lane = t & 63;
    const int q = lane >> 4, c = lane & 15;
    const int wr = (wave >> 1) * 64, wc = (wave & 1) * 64;

    float4v acc[4][4] = {};
    #pragma unroll
    for (int kk = 0; kk < 4; ++kk) {
        short8v af[4], bfr[4];
        #pragma unroll
        for (int ti = 0; ti < 4; ++ti) {
            int row = wr + ti * 16 + c;
            int sc  = (kk * 4 + q) ^ (row & 7);
            af[ti] = *(const short8v*)&As[row * 128 + sc * 8];
        }
        #pragma unroll
        for (int tj = 0; tj < 4; ++tj) {
            int row = wc + tj * 16 + c;
            int sc  = (kk * 4 + q) ^ (row & 7);
            bfr[tj] = *(const short8v*)&Bs[row * 128 + sc * 8];
        }
        #pragma unroll
        for (int ti = 0; ti < 4; ++ti)
            #pragma unroll
            for (int tj = 0; tj < 4; ++tj)
                acc[ti][tj] = __builtin_amdgcn_mfma_f32_16x16x32_bf16(
                    af[ti], bfr[tj], acc[ti][tj], 0, 0, 0);
    }

    // ---- epilogue: C layout col = lane&15 (=c), row = q*4 + reg
    const float NEG_INF = __int_as_float((int)0xFF800000u);
    const float POS_INF = __int_as_float(0x7F800000);

    const int aMin = labs[bm * 128], aMax = labs[bm * 128 + 127];
    const int bMn  = labs[HALF + bn * 128], bMx = labs[HALF + bn * 128 + 127];
    const bool overlap = (aMax >= bMn) && (bMx >= aMin);   // block-uniform

    float sA[16];
    #pragma unroll
    for (int ti = 0; ti < 4; ++ti)
        #pragma unroll
        for (int reg = 0; reg < 4; ++reg)
            sA[ti * 4 + reg] = sq[bm * 128 + wr + ti * 16 + q * 4 + reg];
    float sB[4];
    #pragma unroll
    for (int tj = 0; tj < 4; ++tj)
        sB[tj] = sq[HALF + bn * 128 + wc + tj * 16 + c];

    float rmin[16], rmax[16], cmin[4], cmax[4];
    #pragma unroll
    for (int i = 0; i < 16; ++i) { rmin[i] = POS_INF; rmax[i] = NEG_INF; }
    #pragma unroll
    for (int j = 0; j < 4; ++j)  { cmin[j] = POS_INF; cmax[j] = NEG_INF; }

    if (!overlap) {
        // fast path: every pair is a negative (max side keeps -inf sentinel)
        #pragma unroll
        for (int ti = 0; ti < 4; ++ti)
            #pragma unroll
            for (int tj = 0; tj < 4; ++tj)
                #pragma unroll
                for (int reg = 0; reg < 4; ++reg) {
                    int ri = ti * 4 + reg;
                    float d2 = fmaf(acc[ti][tj][reg], -2.0f, sA[ri] + sB[tj]);
                    rmin[ri] = fminf(rmin[ri], d2);
                    cmin[tj] = fminf(cmin[tj], d2);
                }
    } else {
        int tA[16];
        #pragma unroll
        for (int ti = 0; ti < 4; ++ti)
            #pragma unroll
            for (int reg = 0; reg < 4; ++reg)
                tA[ti * 4 + reg] = labs[bm * 128 + wr + ti * 16 + q * 4 + reg];
        int tB[4];
        #pragma unroll
        for (int tj = 0; tj < 4; ++tj)
            tB[tj] = labs[HALF + bn * 128 + wc + tj * 16 + c];

        #pragma unroll
        for (int ti = 0; ti < 4; ++ti)
            #pragma unroll
            for (int tj = 0; tj < 4; ++tj)
                #pragma unroll
                for (int reg = 0; reg < 4; ++reg) {
                    int ri = ti * 4 + reg;
                    float d2 = fmaf(acc[ti][tj][reg], -2.0f, sA[ri] + sB[tj]);
                    bool same = (tA[ri] == tB[tj]);
                    rmin[ri] = fminf(rmin[ri], same ? POS_INF : d2);
                    rmax[ri] = fmaxf(rmax[ri], same ? d2 : NEG_INF);
                    cmin[tj] = fminf(cmin[tj], same ? POS_INF : d2);
                    cmax[tj] = fmaxf(cmax[tj], same ? d2 : NEG_INF);
                }
    }

    // ---- row partials: DPP reduce across 16 c-lanes, write-once store
    #pragma unroll
    for (int i = 0; i < 16; ++i) {
        rmin[i] = rowmin16(rmin[i]);
        rmax[i] = rowmax16(rmax[i]);
    }
    if (c == 0) {
        const int sR = bn * 2 + (wave & 1);        // unique slot per (bn, col-half)
        #pragma unroll
        for (int ti = 0; ti < 4; ++ti)
            #pragma unroll
            for (int reg = 0; reg < 4; ++reg) {
                int gr = bm * 128 + wr + ti * 16 + q * 4 + reg;
                prow_min[sR * HALF + gr] = rmin[ti * 4 + reg];
                prow_max[sR * HALF + gr] = rmax[ti * 4 + reg];
            }
    }

    // ---- col partials: shuffle reduce across q-groups, write-once store
    #pragma unroll
    for (int m = 16; m <= 32; m <<= 1)
        #pragma unroll
        for (int j = 0; j < 4; ++j) {
            cmin[j] = fminf(cmin[j], __shfl_xor(cmin[j], m, 64));
            cmax[j] = fmaxf(cmax[j], __shfl_xor(cmax[j], m, 64));
        }
    if (q == 0) {
        const int sC = bm * 2 + (wave >> 1);       // unique slot per (bm, row-half)
        #pragma unroll
        for (int tj = 0; tj < 4; ++tj) {
            int gc = bn * 128 + wc + tj * 16 + c;  // local col 0..8191
            pcol_min[sC * HALF + gc] = cmin[tj];
            pcol_max[sC * HALF + gc] = cmax[tj];
        }
    }
}

// ---------------------------------------------------------------------------
// final: reduce 128 partials per element, loss terms -> global accumulators;
// LAST block (ticket) writes d_out.
// ---------------------------------------------------------------------------
__global__ __launch_bounds__(256) void final_kernel(
        const float* __restrict__ prow_min, const float* __restrict__ prow_max,
        const float* __restrict__ pcol_min, const float* __restrict__ pcol_max,
        int* __restrict__ accs /* [accF, accI, ticket] */,
        float* __restrict__ out) {
    const int i = blockIdx.x * 256 + threadIdx.x;   // 64 x 256 = 16384
    const int t = threadIdx.x;
    float* accF = (float*)&accs[0];
    int*   accI = &accs[1];
    int*   tick = &accs[2];

    const float* pmn = (i < HALF) ? prow_min : pcol_min;
    const float* pmx = (i < HALF) ? prow_max : pcol_max;
    const int    li  = (i < HALF) ? i : i - HALF;
    float an2 = pmn[li], ap2 = pmx[li];
    #pragma unroll 8
    for (int p = 1; p < 128; ++p) {
        an2 = fminf(an2, pmn[p * HALF + li]);
        ap2 = fmaxf(ap2, pmx[p * HALF + li]);
    }
    float ap = sqrtf(fmaxf(ap2, 1e-12f));
    float an = sqrtf(fmaxf(an2, 1e-12f));
    float term = fmaxf(ap - an + MARGIN, 0.0f);
    int cnt = (an >= ap) ? 1 : 0;
    #pragma unroll
    for (int m = 1; m < 64; m <<= 1) {
        term += __shfl_xor(term, m, 64);
        cnt  += __shfl_xor(cnt, m, 64);
    }
    __shared__ float sf[4];
    __shared__ int   si[4];
    if ((t & 63) == 0) { sf[t >> 6] = term; si[t >> 6] = cnt; }
    __syncthreads();
    if (t == 0) {
        atomicAdd(accF, sf[0] + sf[1] + sf[2] + sf[3]);
        atomicAdd(accI, si[0] + si[1] + si[2] + si[3]);
        __threadfence();
        int old = atomicAdd(tick, 1);
        if (old == gridDim.x - 1) {
            __threadfence();
            float S = atomicAdd(accF, 0.0f);
            int   C = atomicAdd(accI, 0);
            out[0] = S / (float)N_TOTAL;
            out[1] = (float)C;
        }
    }
}

extern "C" void kernel_launch(void* const* d_in, const int* in_sizes, int n_in,
                              void* d_out, int out_size, void* d_ws, size_t ws_size,
                              hipStream_t stream) {
    const float* X       = (const float*)d_in[0];   // [16384,128] fp32
    const int*   targets = (const int*)d_in[1];     // [16384] int32
    float* out = (float*)d_out;                     // [2]: loss, correct

    char* ws = (char*)d_ws;
    const size_t XB_BYTES = (size_t)N_TOTAL * FEAT * 2;              // 4 MB
    unsigned* Xb    = (unsigned*)ws;
    float* sq       = (float*)(ws + XB_BYTES);                       // 64 KB
    int* labs       = (int*)(ws + XB_BYTES + 65536);                 // 64 KB
    char* p         = ws + XB_BYTES + 2 * 65536;
    float* prow_min = (float*)p;  p += 128 * HALF * 4;               // 4 MB
    float* prow_max = (float*)p;  p += 128 * HALF * 4;               // 4 MB
    float* pcol_min = (float*)p;  p += 128 * HALF * 4;               // 4 MB
    float* pcol_max = (float*)p;  p += 128 * HALF * 4;               // 4 MB
    int* cursor     = (int*)p;    p += 2 * NBINS * 4;                // 8 KB
    int* accs       = (int*)p;                                       // 12 B

    histscan_kernel<<<2, 1024, 0, stream>>>(targets, cursor, accs);
    prep_kernel    <<<4096, 256, 0, stream>>>(X, targets, cursor, Xb, sq, labs);
    cross_kernel   <<<dim3(64, 64), 256, 0, stream>>>(
        (const unsigned short*)Xb, sq, labs, prow_min, prow_max, pcol_min, pcol_max);
    final_kernel   <<<64, 256, 0, stream>>>(
        prow_min, prow_max, pcol_min, pcol_max, accs, out);
}

// Round 12
// 128.079 us; speedup vs baseline: 1.0320x; 1.0320x over previous
//
#include <hip/hip_runtime.h>

#define N_TOTAL 16384
#define HALF    8192
#define FEAT    128
#define MARGIN  0.3f
#define NBINS   1024   // NUM_IDS=1000 <= 1024

typedef __attribute__((ext_vector_type(8))) short  short8v;   // 8 x bf16 (4 VGPRs)
typedef __attribute__((ext_vector_type(4))) float  float4v;   // 4 x f32 acc

__device__ __forceinline__ unsigned short f32_to_bf16_rne(float f) {
    unsigned u = __float_as_uint(f);
    u += 0x7FFFu + ((u >> 16) & 1u);
    return (unsigned short)(u >> 16);
}

// ---- DPP cross-lane min/max within 16-lane rows (VALU pipe, not DS) ------
template<int CTRL>
__device__ __forceinline__ float dpp_mov_f(float x) {
    return __int_as_float(__builtin_amdgcn_update_dpp(
        0, __float_as_int(x), CTRL, 0xF, 0xF, true));
}
__device__ __forceinline__ float rowmin16(float x) {
    x = fminf(x, dpp_mov_f<0xB1>(x));    // quad_perm xor1
    x = fminf(x, dpp_mov_f<0x4E>(x));    // quad_perm xor2
    x = fminf(x, dpp_mov_f<0x141>(x));   // ROW_HALF_MIRROR
    x = fminf(x, dpp_mov_f<0x140>(x));   // ROW_MIRROR
    return x;
}
__device__ __forceinline__ float rowmax16(float x) {
    x = fmaxf(x, dpp_mov_f<0xB1>(x));
    x = fmaxf(x, dpp_mov_f<0x4E>(x));
    x = fmaxf(x, dpp_mov_f<0x141>(x));
    x = fmaxf(x, dpp_mov_f<0x140>(x));
    return x;
}

// ---------------------------------------------------------------------------
// histscan: 2 blocks x 1024 (one per modality half). LDS histogram + scan ->
// cursor (bucket starts). Block 0 zeroes accF/accI/ticket.
// ---------------------------------------------------------------------------
__global__ __launch_bounds__(1024) void histscan_kernel(
        const int* __restrict__ targets, int* __restrict__ cursor,
        int* __restrict__ accs /* [accF, accI, ticket] */) {
    __shared__ int lhist[NBINS];
    const int h = blockIdx.x;
    const int t = threadIdx.x;
    lhist[t] = 0;
    __syncthreads();
    const int* tg = targets + (h << 13);
    #pragma unroll
    for (int k = 0; k < 8; ++k)
        atomicAdd(&lhist[tg[k * 1024 + t]], 1);
    __syncthreads();
    const int lane = t & 63, wave = t >> 6;
    int x = lhist[t];
    const int orig = x;
    #pragma unroll
    for (int m = 1; m < 64; m <<= 1) {
        int v = __shfl_up(x, m, 64);
        if (lane >= m) x += v;
    }
    __shared__ int wsum[16];
    if (lane == 63) wsum[wave] = x;
    __syncthreads();
    if (t == 0) {
        int s = 0;
        for (int w = 0; w < 16; ++w) { int v = wsum[w]; wsum[w] = s; s += v; }
        if (h == 0) { accs[0] = 0; accs[1] = 0; accs[2] = 0; }
    }
    __syncthreads();
    cursor[(h << 10) + t] = x - orig + wsum[wave];
}

// ---------------------------------------------------------------------------
// prep: one wave per ORIGINAL row. Claims sorted slot, converts fp32->bf16,
// writes Xb ROW-MAJOR (256 B/row), bf16 row norms, labels.
// ---------------------------------------------------------------------------
__global__ __launch_bounds__(256) void prep_kernel(
        const float* __restrict__ X, const int* __restrict__ targets,
        int* __restrict__ cursor,
        unsigned* __restrict__ Xb, float* __restrict__ sq, int* __restrict__ labs) {
    const int wave = threadIdx.x >> 6, lane = threadIdx.x & 63;
    const int src = blockIdx.x * 4 + wave;          // original row
    const int h   = src >> 13;
    const int lbl = targets[src];
    int dst;
    if (lane == 0)
        dst = (h << 13) + atomicAdd(&cursor[(h << 10) + lbl], 1);
    dst = __shfl(dst, 0, 64);
    const float2 xv = ((const float2*)(X + (size_t)src * FEAT))[lane];
    unsigned short h0 = f32_to_bf16_rne(xv.x);
    unsigned short h1 = f32_to_bf16_rne(xv.y);
    Xb[dst * 64 + lane] = (unsigned)h0 | ((unsigned)h1 << 16);
    float x0 = __uint_as_float((unsigned)h0 << 16);
    float x1 = __uint_as_float((unsigned)h1 << 16);
    float p = x0 * x0 + x1 * x1;
    #pragma unroll
    for (int m = 1; m < 64; m <<= 1) p += __shfl_xor(p, m, 64);
    if (lane == 0) {
        sq[dst]   = p;
        labs[dst] = lbl;
    }
}

// ---------------------------------------------------------------------------
// main: round-11 structure (128x128 LDS tile, 4096 blocks, XOR-swizzled
// staging, write-once partial stores) + NEW: per-block sq/labs slices staged
// into LDS with the tile, so the epilogue's ~44 VMEM table loads become
// cheap broadcast ds_reads (they were the post-MFMA latency serializer).
// ---------------------------------------------------------------------------
__global__ __launch_bounds__(256, 2) void cross_kernel(
        const unsigned short* __restrict__ Xb, const float* __restrict__ sq,
        const int* __restrict__ labs,
        float* __restrict__ prow_min, float* __restrict__ prow_max,   // [128][HALF]
        float* __restrict__ pcol_min, float* __restrict__ pcol_max) { // [128][HALF]
    __shared__ unsigned short As[128 * 128];
    __shared__ unsigned short Bs[128 * 128];
    __shared__ float SsqA[128], SsqB[128];
    __shared__ int   SlabA[128], SlabB[128];
    const int bm = blockIdx.x, bn = blockIdx.y;
    const int t  = threadIdx.x;

    const unsigned short* Ag = Xb + (size_t)bm * 128 * FEAT;
    const unsigned short* Bg = Xb + (size_t)(HALF + bn * 128) * FEAT;
    #pragma unroll
    for (int p = 0; p < 8; ++p) {
        int idx = p * 256 + t;            // 16B chunk id, 0..2047
        int row = idx >> 4, ch = idx & 15;
        int sc  = ch ^ (row & 7);
        uint4 va = ((const uint4*)Ag)[idx];
        uint4 vb = ((const uint4*)Bg)[idx];
        *(uint4*)&As[row * 128 + sc * 8] = va;
        *(uint4*)&Bs[row * 128 + sc * 8] = vb;
    }
    if (t < 128) {                        // stage scalar tables (2 KB)
        SsqA[t]  = sq[bm * 128 + t];
        SsqB[t]  = sq[HALF + bn * 128 + t];
        SlabA[t] = labs[bm * 128 + t];
        SlabB[t] = labs[HALF + bn * 128 + t];
    }
    __syncthreads();

    const int wave = t >> 6, lane = t & 63;
    const int q = lane >> 4, c = lane & 15;
    const int wr = (wave >> 1) * 64, wc = (wave & 1) * 64;

    float4v acc[4][4] = {};
    #pragma unroll
    for (int kk = 0; kk < 4; ++kk) {
        short8v af[4], bfr[4];
        #pragma unroll
        for (int ti = 0; ti < 4; ++ti) {
            int row = wr + ti * 16 + c;
            int sc  = (kk * 4 + q) ^ (row & 7);
            af[ti] = *(const short8v*)&As[row * 128 + sc * 8];
        }
        #pragma unroll
        for (int tj = 0; tj < 4; ++tj) {
            int row = wc + tj * 16 + c;
            int sc  = (kk * 4 + q) ^ (row & 7);
            bfr[tj] = *(const short8v*)&Bs[row * 128 + sc * 8];
        }
        #pragma unroll
        for (int ti = 0; ti < 4; ++ti)
            #pragma unroll
            for (int tj = 0; tj < 4; ++tj)
                acc[ti][tj] = __builtin_amdgcn_mfma_f32_16x16x32_bf16(
                    af[ti], bfr[tj], acc[ti][tj], 0, 0, 0);
    }

    // ---- epilogue: C layout col = lane&15 (=c), row = q*4 + reg
    const float NEG_INF = __int_as_float((int)0xFF800000u);
    const float POS_INF = __int_as_float(0x7F800000);

    const int aMin = SlabA[0], aMax = SlabA[127];
    const int bMn  = SlabB[0], bMx  = SlabB[127];
    const bool overlap = (aMax >= bMn) && (bMx >= aMin);   // block-uniform

    float sA[16];
    #pragma unroll
    for (int ti = 0; ti < 4; ++ti)
        #pragma unroll
        for (int reg = 0; reg < 4; ++reg)
            sA[ti * 4 + reg] = SsqA[wr + ti * 16 + q * 4 + reg];   // broadcast read
    float sB[4];
    #pragma unroll
    for (int tj = 0; tj < 4; ++tj)
        sB[tj] = SsqB[wc + tj * 16 + c];                           // 16-bank read

    float rmin[16], rmax[16], cmin[4], cmax[4];
    #pragma unroll
    for (int i = 0; i < 16; ++i) { rmin[i] = POS_INF; rmax[i] = NEG_INF; }
    #pragma unroll
    for (int j = 0; j < 4; ++j)  { cmin[j] = POS_INF; cmax[j] = NEG_INF; }

    if (!overlap) {
        // fast path: every pair is a negative (max side keeps -inf sentinel)
        #pragma unroll
        for (int ti = 0; ti < 4; ++ti)
            #pragma unroll
            for (int tj = 0; tj < 4; ++tj)
                #pragma unroll
                for (int reg = 0; reg < 4; ++reg) {
                    int ri = ti * 4 + reg;
                    float d2 = fmaf(acc[ti][tj][reg], -2.0f, sA[ri] + sB[tj]);
                    rmin[ri] = fminf(rmin[ri], d2);
                    cmin[tj] = fminf(cmin[tj], d2);
                }
    } else {
        int tA[16];
        #pragma unroll
        for (int ti = 0; ti < 4; ++ti)
            #pragma unroll
            for (int reg = 0; reg < 4; ++reg)
                tA[ti * 4 + reg] = SlabA[wr + ti * 16 + q * 4 + reg];
        int tB[4];
        #pragma unroll
        for (int tj = 0; tj < 4; ++tj)
            tB[tj] = SlabB[wc + tj * 16 + c];

        #pragma unroll
        for (int ti = 0; ti < 4; ++ti)
            #pragma unroll
            for (int tj = 0; tj < 4; ++tj)
                #pragma unroll
                for (int reg = 0; reg < 4; ++reg) {
                    int ri = ti * 4 + reg;
                    float d2 = fmaf(acc[ti][tj][reg], -2.0f, sA[ri] + sB[tj]);
                    bool same = (tA[ri] == tB[tj]);
                    rmin[ri] = fminf(rmin[ri], same ? POS_INF : d2);
                    rmax[ri] = fmaxf(rmax[ri], same ? d2 : NEG_INF);
                    cmin[tj] = fminf(cmin[tj], same ? POS_INF : d2);
                    cmax[tj] = fmaxf(cmax[tj], same ? d2 : NEG_INF);
                }
    }

    // ---- row partials: DPP reduce across 16 c-lanes, write-once store
    #pragma unroll
    for (int i = 0; i < 16; ++i) {
        rmin[i] = rowmin16(rmin[i]);
        rmax[i] = rowmax16(rmax[i]);
    }
    if (c == 0) {
        const int sR = bn * 2 + (wave & 1);        // unique slot per (bn, col-half)
        #pragma unroll
        for (int ti = 0; ti < 4; ++ti)
            #pragma unroll
            for (int reg = 0; reg < 4; ++reg) {
                int gr = bm * 128 + wr + ti * 16 + q * 4 + reg;
                prow_min[sR * HALF + gr] = rmin[ti * 4 + reg];
                prow_max[sR * HALF + gr] = rmax[ti * 4 + reg];
            }
    }

    // ---- col partials: shuffle reduce across q-groups, write-once store
    #pragma unroll
    for (int m = 16; m <= 32; m <<= 1)
        #pragma unroll
        for (int j = 0; j < 4; ++j) {
            cmin[j] = fminf(cmin[j], __shfl_xor(cmin[j], m, 64));
            cmax[j] = fmaxf(cmax[j], __shfl_xor(cmax[j], m, 64));
        }
    if (q == 0) {
        const int sC = bm * 2 + (wave >> 1);       // unique slot per (bm, row-half)
        #pragma unroll
        for (int tj = 0; tj < 4; ++tj) {
            int gc = bn * 128 + wc + tj * 16 + c;  // local col 0..8191
            pcol_min[sC * HALF + gc] = cmin[tj];
            pcol_max[sC * HALF + gc] = cmax[tj];
        }
    }
}

// ---------------------------------------------------------------------------
// final: reduce 128 partials per element, loss terms -> global accumulators;
// LAST block (ticket) writes d_out.
// ---------------------------------------------------------------------------
__global__ __launch_bounds__(256) void final_kernel(
        const float* __restrict__ prow_min, const float* __restrict__ prow_max,
        const float* __restrict__ pcol_min, const float* __restrict__ pcol_max,
        int* __restrict__ accs /* [accF, accI, ticket] */,
        float* __restrict__ out) {
    const int i = blockIdx.x * 256 + threadIdx.x;   // 64 x 256 = 16384
    const int t = threadIdx.x;
    float* accF = (float*)&accs[0];
    int*   accI = &accs[1];
    int*   tick = &accs[2];

    const float* pmn = (i < HALF) ? prow_min : pcol_min;
    const float* pmx = (i < HALF) ? prow_max : pcol_max;
    const int    li  = (i < HALF) ? i : i - HALF;
    float an2 = pmn[li], ap2 = pmx[li];
    #pragma unroll 8
    for (int p = 1; p < 128; ++p) {
        an2 = fminf(an2, pmn[p * HALF + li]);
        ap2 = fmaxf(ap2, pmx[p * HALF + li]);
    }
    float ap = sqrtf(fmaxf(ap2, 1e-12f));
    float an = sqrtf(fmaxf(an2, 1e-12f));
    float term = fmaxf(ap - an + MARGIN, 0.0f);
    int cnt = (an >= ap) ? 1 : 0;
    #pragma unroll
    for (int m = 1; m < 64; m <<= 1) {
        term += __shfl_xor(term, m, 64);
        cnt  += __shfl_xor(cnt, m, 64);
    }
    __shared__ float sf[4];
    __shared__ int   si[4];
    if ((t & 63) == 0) { sf[t >> 6] = term; si[t >> 6] = cnt; }
    __syncthreads();
    if (t == 0) {
        atomicAdd(accF, sf[0] + sf[1] + sf[2] + sf[3]);
        atomicAdd(accI, si[0] + si[1] + si[2] + si[3]);
        __threadfence();
        int old = atomicAdd(tick, 1);
        if (old == gridDim.x - 1) {
            __threadfence();
            float S = atomicAdd(accF, 0.0f);
            int   C = atomicAdd(accI, 0);
            out[0] = S / (float)N_TOTAL;
            out[1] = (float)C;
        }
    }
}

extern "C" void kernel_launch(void* const* d_in, const int* in_sizes, int n_in,
                              void* d_out, int out_size, void* d_ws, size_t ws_size,
                              hipStream_t stream) {
    const float* X       = (const float*)d_in[0];   // [16384,128] fp32
    const int*   targets = (const int*)d_in[1];     // [16384] int32
    float* out = (float*)d_out;                     // [2]: loss, correct

    char* ws = (char*)d_ws;
    const size_t XB_BYTES = (size_t)N_TOTAL * FEAT * 2;              // 4 MB
    unsigned* Xb    = (unsigned*)ws;
    float* sq       = (float*)(ws + XB_BYTES);                       // 64 KB
    int* labs       = (int*)(ws + XB_BYTES + 65536);                 // 64 KB
    char* p         = ws + XB_BYTES + 2 * 65536;
    float* prow_min = (float*)p;  p += 128 * HALF * 4;               // 4 MB
    float* prow_max = (float*)p;  p += 128 * HALF * 4;               // 4 MB
    float* pcol_min = (float*)p;  p += 128 * HALF * 4;               // 4 MB
    float* pcol_max = (float*)p;  p += 128 * HALF * 4;               // 4 MB
    int* cursor     = (int*)p;    p += 2 * NBINS * 4;                // 8 KB
    int* accs       = (int*)p;                                       // 12 B

    histscan_kernel<<<2, 1024, 0, stream>>>(targets, cursor, accs);
    prep_kernel    <<<4096, 256, 0, stream>>>(X, targets, cursor, Xb, sq, labs);
    cross_kernel   <<<dim3(64, 64), 256, 0, stream>>>(
        (const unsigned short*)Xb, sq, labs, prow_min, prow_max, pcol_min, pcol_max);
    final_kernel   <<<64, 256, 0, stream>>>(
        prow_min, prow_max, pcol_min, pcol_max, accs, out);
}